// Round 10
// baseline (193.431 us; speedup 1.0000x reference)
//
#include <hip/hip_runtime.h>
#include <hip/hip_bf16.h>

#define N_NODES 100000
#define DEG 16
#define D 128

typedef __bf16 bf16x8 __attribute__((ext_vector_type(8)));
typedef float f32x4 __attribute__((ext_vector_type(4)));
typedef float f32x2 __attribute__((ext_vector_type(2)));
typedef unsigned u32x4 __attribute__((ext_vector_type(4)));
typedef unsigned u32x2 __attribute__((ext_vector_type(2)));

// swizzled element index into a [128][128] ushort tile (XOR bits 3..5 of k with row bits 0..2)
__device__ __forceinline__ int swz(int row, int k) {
  return (row << 7) + (k ^ ((row & 7) << 3));
}

// Kernel 0: W [k][n] f32 -> Wt bf16 transposed [n][k], swizzled (64 blocks, 1 elem/thread)
__global__ void k_convW(const float* __restrict__ W, ushort* __restrict__ Wt) {
  int pos = (blockIdx.x << 8) + threadIdx.x;   // 0..16383
  int k = pos >> 7, n = pos & 127;
  union { __bf16 h; ushort u; } c;
  c.h = (__bf16)W[pos];
  Wt[swz(n, k)] = c.u;
}

// Kernel 1: Xp = bf16(X @ W) in LOGICAL row-major layout.
// 128-row tile per block, 4 waves x 32 rows. B-fragments direct from L1-resident Wt.
// Epilogue: per-wave LDS transpose (acc fragments -> contiguous rows) then coalesced stores.
__global__ __launch_bounds__(256) void k_gemm(const float* __restrict__ X,
                                              const ushort* __restrict__ Wt,
                                              ushort* __restrict__ Xp) {
  __shared__ __align__(16) ushort Cs[4][32 * 128];   // 8 KB per wave
  const int tid = threadIdx.x;
  const int row0 = blockIdx.x << 7;
  const int wave = tid >> 6;
  const int lane = tid & 63;
  const int lhi = lane >> 4;           // 0..3
  const int llo = lane & 15;

  // issue all 16 A-fragment loads: lane owns row (per m), k-slice lhi*8 (per t)
  float4 t0[2][4], t1[2][4];
#pragma unroll
  for (int m = 0; m < 2; ++m) {
    int row = row0 + (wave << 5) + (m << 4) + llo;
    const float* rp = X + row * D + (lhi << 3);
    bool ok = row < N_NODES;
#pragma unroll
    for (int t = 0; t < 4; ++t) {
      t0[m][t] = ok ? *(const float4*)(rp + (t << 5)) : make_float4(0.f, 0.f, 0.f, 0.f);
      t1[m][t] = ok ? *(const float4*)(rp + (t << 5) + 4) : make_float4(0.f, 0.f, 0.f, 0.f);
    }
  }

  // convert A to bf16
  bf16x8 af[2][4];
#pragma unroll
  for (int m = 0; m < 2; ++m)
#pragma unroll
    for (int t = 0; t < 4; ++t) {
      bf16x8 v;
      v[0] = (__bf16)t0[m][t].x; v[1] = (__bf16)t0[m][t].y;
      v[2] = (__bf16)t0[m][t].z; v[3] = (__bf16)t0[m][t].w;
      v[4] = (__bf16)t1[m][t].x; v[5] = (__bf16)t1[m][t].y;
      v[6] = (__bf16)t1[m][t].z; v[7] = (__bf16)t1[m][t].w;
      af[m][t] = v;
    }

  f32x4 acc[2][8];
#pragma unroll
  for (int m = 0; m < 2; ++m)
#pragma unroll
    for (int n = 0; n < 8; ++n)
      acc[m][n] = (f32x4){0.f, 0.f, 0.f, 0.f};

#pragma unroll
  for (int t = 0; t < 4; ++t) {
    const int k0 = (t << 5) + (lhi << 3);
    bf16x8 b[8];
#pragma unroll
    for (int n = 0; n < 8; ++n)
      b[n] = *(const bf16x8*)(Wt + swz((n << 4) + llo, k0));
#pragma unroll
    for (int m = 0; m < 2; ++m)
#pragma unroll
      for (int n = 0; n < 8; ++n)
        acc[m][n] = __builtin_amdgcn_mfma_f32_16x16x32_bf16(af[m][t], b[n], acc[m][n], 0, 0, 0);
  }

  // --- epilogue: LDS transpose to logical layout ---
  // write: value (m,n,r) of lane (lhi,llo) is row_local rl=m*16+lhi*4+r, col n*16+llo.
  // store at ushort offset rl*128 + (n^(rl&7))*16 + llo  (XOR swizzle vs bank conflicts)
  ushort* cs = &Cs[wave][0];
#pragma unroll
  for (int m = 0; m < 2; ++m)
#pragma unroll
    for (int n = 0; n < 8; ++n)
#pragma unroll
      for (int r = 0; r < 4; ++r) {
        int rl = (m << 4) + (lhi << 2) + r;
        union { __bf16 h; ushort u; } c;
        c.h = (__bf16)acc[m][n][r];
        cs[(rl << 7) + ((n ^ (rl & 7)) << 4) + llo] = c.u;
      }
  __syncthreads();
  // read back linear: 8 passes, 4 rows/pass, 16 lanes x 16 B per row
#pragma unroll
  for (int p = 0; p < 8; ++p) {
    int o = (p << 9) + (lane << 3);        // ushort offset in wave region
    int rl = o >> 7;                        // local row 0..31
    int h = (o & 127) >> 3;                 // uint4 group 0..15 within row
    int n = (h >> 1) ^ (rl & 7);
    u32x4 v = *(const u32x4*)(cs + (rl << 7) + (n << 4) + ((h & 1) << 3));
    int grow = row0 + (wave << 5) + rl;
    if (grow < N_NODES)
      __builtin_nontemporal_store(v, (u32x4*)(Xp + grow * D + (h << 3)));
  }
}

// Kernel 2 (column-sliced): block b -> slice s=b&7 (logical cols [16s,16s+16)), chunk=b>>3.
// With round-robin blockIdx->XCD, each XCD's L2 only sees a 3.2 MB column slice of Xp ->
// gathers become L2 hits. Wave handles 8 rows/iter: lane (r=lane>>3, c2=lane&7) gathers
// 4 B (2 cols) per edge, accumulates 16 edges serially, stores float2 (64 B/row-slice).
__global__ __launch_bounds__(256) void k_spmm(const ushort* __restrict__ Xp,
                                              const int* __restrict__ ci,
                                              float* __restrict__ out) {
  const int slice = blockIdx.x & 7;
  const int chunk = blockIdx.x >> 3;
  const int wave = threadIdx.x >> 6;
  const int lane = threadIdx.x & 63;
  const int r = lane >> 3;
  const int c2 = lane & 7;
  const int row8 = (chunk << 5) + (wave << 3);   // 3125*32 = 100000 exact, no tail

  // 128 indices for rows row8..row8+7 (2 per lane, coalesced)
  u32x2 iv = __builtin_nontemporal_load((const u32x2*)(ci + row8 * DEG) + lane);

  const ushort* tb = Xp + (slice << 4) + (c2 << 1);
  float a0 = 0.f, a1 = 0.f;
#pragma unroll
  for (int e = 0; e < DEG; ++e) {
    int src = (lane & 0x38) + (e >> 1);
    int idx = __shfl((e & 1) ? (int)iv.y : (int)iv.x, src);
    unsigned v = *(const unsigned*)(tb + idx * D);
    a0 += __uint_as_float(v << 16);
    a1 += __uint_as_float(v & 0xffff0000u);
  }

  f32x2 st = {a0, a1};
  __builtin_nontemporal_store(st, (f32x2*)(out + (row8 + r) * D + (slice << 4) + (c2 << 1)));
}

extern "C" void kernel_launch(void* const* d_in, const int* in_sizes, int n_in,
                              void* d_out, int out_size, void* d_ws, size_t ws_size,
                              hipStream_t stream) {
  const float* X = (const float*)d_in[0];
  const float* W = (const float*)d_in[1];
  const int* ci = (const int*)d_in[3];

  ushort* Wt = (ushort*)d_ws;                 // 32 KB
  ushort* Xp = (ushort*)d_ws + 128 * 128;     // 25.6 MB bf16 X' (logical layout)
  float* out = (float*)d_out;

  k_convW<<<64, 256, 0, stream>>>(W, Wt);
  k_gemm<<<(N_NODES + 127) / 128, 256, 0, stream>>>(X, Wt, Xp);
  k_spmm<<<3125 * 8, 256, 0, stream>>>(Xp, ci, out);
}

// Round 11
// 86.861 us; speedup vs baseline: 2.2269x; 2.2269x over previous
//
#include <hip/hip_runtime.h>
#include <hip/hip_bf16.h>

#define N_NODES 100000
#define DEG 16
#define D 128

typedef __bf16 bf16x8 __attribute__((ext_vector_type(8)));
typedef float f32x4 __attribute__((ext_vector_type(4)));

__device__ __forceinline__ unsigned pk2(float a, float b) {
  union { __bf16 h[2]; unsigned u; } x;
  x.h[0] = (__bf16)a; x.h[1] = (__bf16)b;
  return x.u;
}

// swizzled element index into a [128][128] ushort LDS tile (XOR bits 3..5 of k with row bits 0..2)
__device__ __forceinline__ int swz(int row, int k) {
  return (row << 7) + (k ^ ((row & 7) << 3));
}

// Kernel 1: Xp = bf16(X @ W), rows stored in permuted col order: pos p=llo*8+n <-> col n*16+llo.
// 128-row tile per block, 4 waves x 32 rows. W conversion FUSED: each block converts the
// 64 KB f32 W (L1/L3-resident) into the swizzled bf16 LDS tile itself — no convW kernel,
// no global Wt. A-loads issued first so X latency hides under W staging; one barrier; MFMA.
__global__ __launch_bounds__(256) void k_gemm(const float* __restrict__ X,
                                              const float* __restrict__ W,
                                              ushort* __restrict__ Xp) {
  __shared__ __align__(16) ushort Ws[128 * 128];
  const int tid = threadIdx.x;
  const int row0 = blockIdx.x << 7;
  const int wave = tid >> 6;
  const int lane = tid & 63;
  const int lhi = lane >> 4;           // 0..3
  const int llo = lane & 15;

  // 1) issue all 16 A-fragment loads first: lane owns row (per m), k-slice lhi*8 (per t)
  float4 t0[2][4], t1[2][4];
#pragma unroll
  for (int m = 0; m < 2; ++m) {
    int row = row0 + (wave << 5) + (m << 4) + llo;
    const float* rp = X + row * D + (lhi << 3);
    bool ok = row < N_NODES;
#pragma unroll
    for (int t = 0; t < 4; ++t) {
      t0[m][t] = ok ? *(const float4*)(rp + (t << 5)) : make_float4(0.f, 0.f, 0.f, 0.f);
      t1[m][t] = ok ? *(const float4*)(rp + (t << 5) + 4) : make_float4(0.f, 0.f, 0.f, 0.f);
    }
  }

  // 2) stage W -> swizzled bf16 LDS (thread t converts 64 elems via 16 float4 loads)
#pragma unroll
  for (int jj = 0; jj < 16; ++jj) {
    int base = (jj << 10) + (tid << 2);        // element index in W [k][n]
    int k = base >> 7, n0 = base & 127;
    float4 w = *(const float4*)(W + base);
    union { __bf16 h; ushort u; } c0, c1, c2, c3;
    c0.h = (__bf16)w.x; c1.h = (__bf16)w.y; c2.h = (__bf16)w.z; c3.h = (__bf16)w.w;
    Ws[swz(n0 + 0, k)] = c0.u;
    Ws[swz(n0 + 1, k)] = c1.u;
    Ws[swz(n0 + 2, k)] = c2.u;
    Ws[swz(n0 + 3, k)] = c3.u;
  }

  // 3) convert A to bf16 (first use of A loads -> waits here, after staging issued)
  bf16x8 af[2][4];
#pragma unroll
  for (int m = 0; m < 2; ++m)
#pragma unroll
    for (int t = 0; t < 4; ++t) {
      bf16x8 v;
      v[0] = (__bf16)t0[m][t].x; v[1] = (__bf16)t0[m][t].y;
      v[2] = (__bf16)t0[m][t].z; v[3] = (__bf16)t0[m][t].w;
      v[4] = (__bf16)t1[m][t].x; v[5] = (__bf16)t1[m][t].y;
      v[6] = (__bf16)t1[m][t].z; v[7] = (__bf16)t1[m][t].w;
      af[m][t] = v;
    }
  __syncthreads();

  f32x4 acc[2][8];
#pragma unroll
  for (int m = 0; m < 2; ++m)
#pragma unroll
    for (int n = 0; n < 8; ++n)
      acc[m][n] = (f32x4){0.f, 0.f, 0.f, 0.f};

#pragma unroll
  for (int t = 0; t < 4; ++t) {
    const int k0 = (t << 5) + (lhi << 3);
    bf16x8 b[8];
#pragma unroll
    for (int n = 0; n < 8; ++n)
      b[n] = *(const bf16x8*)(Ws + swz((n << 4) + llo, k0));
#pragma unroll
    for (int m = 0; m < 2; ++m)
#pragma unroll
      for (int n = 0; n < 8; ++n)
        acc[m][n] = __builtin_amdgcn_mfma_f32_16x16x32_bf16(af[m][t], b[n], acc[m][n], 0, 0, 0);
  }

  // epilogue: C/D layout col=llo, row=lhi*4+r. Pack 8 cols (n=0..7) -> uint4 per (m,r).
#pragma unroll
  for (int m = 0; m < 2; ++m) {
#pragma unroll
    for (int r = 0; r < 4; ++r) {
      int row = row0 + (wave << 5) + (m << 4) + (lhi << 2) + r;
      if (row < N_NODES) {
        uint4 v;
        v.x = pk2(acc[m][0][r], acc[m][1][r]);
        v.y = pk2(acc[m][2][r], acc[m][3][r]);
        v.z = pk2(acc[m][4][r], acc[m][5][r]);
        v.w = pk2(acc[m][6][r], acc[m][7][r]);
        *(uint4*)(Xp + row * D + (llo << 3)) = v;
      }
    }
  }
}

// Kernel 2: out[i] = sum_{e} Xp[ci[e]]  (one wave per row; Xp rows are col-permuted)
// Quarter-wave scheme: group g = lane>>4 handles edges 4g..4g+3; lane j = lane&15
// loads 16 B (positions j*8..j*8+8 = logical cols {n*16+j}). Cross-group reduce
// via shfl_xor(16,32); group-g store covers contiguous cols 32g..32g+31.
__global__ __launch_bounds__(256) void k_spmm(const ushort* __restrict__ Xp,
                                              const int* __restrict__ ci,
                                              float* __restrict__ out) {
  const int wave = threadIdx.x >> 6;
  const int lane = threadIdx.x & 63;
  const int row = (blockIdx.x << 2) + wave;
  if (row >= N_NODES) return;
  const int g = lane >> 4;
  const int j = lane & 15;

  int idx = 0;
  if (lane < DEG) idx = __builtin_nontemporal_load(ci + row * DEG + lane);

  uint4 v[4];
#pragma unroll
  for (int e = 0; e < 4; ++e) {
    int col = __shfl(idx, (g << 2) + e);
    v[e] = *(const uint4*)(Xp + col * D + (j << 3));
  }

  float acc[8];
#pragma unroll
  for (int n = 0; n < 8; ++n) acc[n] = 0.f;
#pragma unroll
  for (int e = 0; e < 4; ++e) {
    acc[0] += __uint_as_float(v[e].x << 16);
    acc[1] += __uint_as_float(v[e].x & 0xffff0000u);
    acc[2] += __uint_as_float(v[e].y << 16);
    acc[3] += __uint_as_float(v[e].y & 0xffff0000u);
    acc[4] += __uint_as_float(v[e].z << 16);
    acc[5] += __uint_as_float(v[e].z & 0xffff0000u);
    acc[6] += __uint_as_float(v[e].w << 16);
    acc[7] += __uint_as_float(v[e].w & 0xffff0000u);
  }

#pragma unroll
  for (int n = 0; n < 8; ++n) {
    acc[n] += __shfl_xor(acc[n], 16);
    acc[n] += __shfl_xor(acc[n], 32);
  }

  // lane (g,j): acc[n] holds col n*16+j; store acc[2g]->col 32g+j, acc[2g+1]->col 32g+16+j
  float* op = out + row * D + (g << 5) + j;
  __builtin_nontemporal_store(acc[(g << 1)], op);
  __builtin_nontemporal_store(acc[(g << 1) + 1], op + 16);
}

extern "C" void kernel_launch(void* const* d_in, const int* in_sizes, int n_in,
                              void* d_out, int out_size, void* d_ws, size_t ws_size,
                              hipStream_t stream) {
  const float* X = (const float*)d_in[0];
  const float* W = (const float*)d_in[1];
  const int* ci = (const int*)d_in[3];

  ushort* Xp = (ushort*)d_ws + 128 * 128;     // 25.6 MB bf16 X' (permuted rows)
  float* out = (float*)d_out;

  k_gemm<<<(N_NODES + 127) / 128, 256, 0, stream>>>(X, W, Xp);
  k_spmm<<<N_NODES / 4, 256, 0, stream>>>(Xp, ci, out);
}